// Round 1
// baseline (237.656 us; speedup 1.0000x reference)
//
#include <hip/hip_runtime.h>

namespace {
constexpr int kB = 16, kT = 2048, kC = 512, kH = 4, kU = 250, kDH = 128;
constexpr int kDS = 4;          // d-split blocks per (b,h)
constexpr int kDW = 32;         // d per block
constexpr int kTT = 256;        // t per staging tile
constexpr int kNST = kT / kTT;  // 8
constexpr int kPitch = 2056;    // V row pitch in shorts: dword stride 1028 == 4 mod 32 (2-way, free)
constexpr int kNB = kDS * kH * kB;  // 256 blocks == 1 per CU, all co-resident
}

typedef __attribute__((ext_vector_type(8))) short short8;
typedef __attribute__((ext_vector_type(4))) float float4v;

__device__ __forceinline__ short f2bf(float x) {
    union { float f; unsigned int u; } v; v.f = x;
    unsigned int r = (v.u + 0x7FFFu + ((v.u >> 16) & 1u)) >> 16;
    return (short)r;
}

// Single fused kernel. grid (ds=4, h=4, b=16) = 256 blocks x 1024 thr (1 block/CU).
// Phase A: stage own c-slice [cbase, cbase+32) x all T as bf16 V into LDS (hidden read
//   ONCE for the whole net), and compute this slice's f32 contribution to the alpha
//   logit (depthwise conv needs only t-neighbors of the same channel). Partials are
//   atomicAdd'ed into alpha_acc[b][t] (zeroed by host-side memset).
// Grid barrier: manual arrive+spin on a zeroed counter (all 256 blocks resident).
// Phase B: previous k3 logic, but V is already LDS-resident: scan -> al_s, exact
//   softmax max via binary search, banded chunk loop with MFMA -- zero barriers.
__global__ __launch_bounds__(1024) void fused_pif(
    const float* __restrict__ hid, const float* __restrict__ mask,
    const int* __restrict__ target, const float* __restrict__ sigma,
    const float* __restrict__ conv_w, const float* __restrict__ conv_b,
    const float* __restrict__ lin_w, const float* __restrict__ lin_b,
    float* __restrict__ alpha_acc, unsigned int* __restrict__ counter,
    float* __restrict__ out_ac, float* __restrict__ out_tok, float* __restrict__ out_alpha)
{
    __shared__ unsigned short bV[kDW * kPitch];   // 131584 B: [d][t] bf16, all T
    __shared__ float al_s[kT];                    // 8 KB alignment
    __shared__ float wedge[16][8][8];             // 4 KB wave-edge f32 {a0,a1}
    __shared__ float tedge[2][8][8];              // 512 B tile-edge, dbuf by st&1
    __shared__ float woff[16];
    __shared__ float s_tot;

    const int ds = blockIdx.x, h = blockIdx.y, b = blockIdx.z;
    const int tid = threadIdx.x;
    const int wave = tid >> 6, lane = tid & 63;
    const int dl = tid & 7;          // c-quad within slice (4 c each)
    const int p  = tid >> 3;         // t-pair index within tile (0..127)
    const int pl = lane >> 3;        // p position within wave (0..7)
    const int cbase = h * kDH + ds * kDW;
    const int c0g = cbase + dl * 4;

    // ---- per-thread conv/linear weights for my 4 channels (f32, exact) ----
    float cw0[4], cw1[4], cw2[4], cb4[4], lw4[4];
    {
        float4 w0 = *(const float4*)(conv_w + c0g * 3);
        float4 w1 = *(const float4*)(conv_w + c0g * 3 + 4);
        float4 w2 = *(const float4*)(conv_w + c0g * 3 + 8);
        cw0[0] = w0.x; cw1[0] = w0.y; cw2[0] = w0.z;
        cw0[1] = w0.w; cw1[1] = w1.x; cw2[1] = w1.y;
        cw0[2] = w1.z; cw1[2] = w1.w; cw2[2] = w2.x;
        cw0[3] = w2.y; cw1[3] = w2.z; cw2[3] = w2.w;
        *(float4*)cb4 = *(const float4*)(conv_b + c0g);
        *(float4*)lw4 = *(const float4*)(lin_w + c0g);
    }
    float* acc_g = alpha_acc + (size_t)b * kT;
    const float* hrow = hid + (size_t)b * kT * kC + c0g;

    // ---- Phase A: stage V (bf16) + f32 conv/linear partials, tile by tile ----
    float4 a0, a1;
    {
        const float* s = hrow + (size_t)(2 * p) * kC;
        a0 = *(const float4*)s;
        a1 = *(const float4*)(s + kC);
    }
    for (int st = 0; st < kNST; st++) {
        // bf16 V into LDS
        #pragma unroll
        for (int e = 0; e < 4; e++) {
            unsigned int lo = (unsigned int)(unsigned short)f2bf(((const float*)&a0)[e]);
            unsigned int hi = (unsigned int)(unsigned short)f2bf(((const float*)&a1)[e]);
            *(unsigned int*)&bV[(dl * 4 + e) * kPitch + st * kTT + 2 * p] = lo | (hi << 16);
        }
        // publish edge rows (f32) for cross-wave / cross-tile conv neighbors
        if (pl == 7) {
            *(float4*)&wedge[wave][dl][0] = a0;
            *(float4*)&wedge[wave][dl][4] = a1;
            if (wave == 15) {
                *(float4*)&tedge[st & 1][dl][0] = a0;
                *(float4*)&tedge[st & 1][dl][4] = a1;
            }
        }
        // prefetch next tile before the barrier (latency hides behind conv)
        float4 n0 = a0, n1 = a1;
        if (st + 1 < kNST) {
            const float* s = hrow + (size_t)((st + 1) * kTT + 2 * p) * kC;
            n0 = *(const float4*)s;
            n1 = *(const float4*)(s + kC);
        }
        __syncthreads();                          // B1: edges + V visible

        // neighbors h[t0-2], h[t0-1] (t0 = st*256 + 2p)
        float pm2[4], pm1[4];
        #pragma unroll
        for (int e = 0; e < 4; e++) {
            pm2[e] = __shfl_up(((const float*)&a0)[e], 8, 64);
            pm1[e] = __shfl_up(((const float*)&a1)[e], 8, 64);
        }
        if (pl == 0) {
            if (wave > 0) {
                *(float4*)pm2 = *(const float4*)&wedge[wave - 1][dl][0];
                *(float4*)pm1 = *(const float4*)&wedge[wave - 1][dl][4];
            } else if (st > 0) {
                *(float4*)pm2 = *(const float4*)&tedge[(st - 1) & 1][dl][0];
                *(float4*)pm1 = *(const float4*)&tedge[(st - 1) & 1][dl][4];
            } else {
                pm2[0] = pm2[1] = pm2[2] = pm2[3] = 0.f;
                pm1[0] = pm1[1] = pm1[2] = pm1[3] = 0.f;
            }
        }
        // conv outputs at t0-1 and t0 (covers tile offsets -1..254; 255 done by next tile)
        float s_m1 = 0.f, s_0 = 0.f;
        #pragma unroll
        for (int e = 0; e < 4; e++) {
            float x_m2 = pm2[e], x_m1 = pm1[e];
            float x0 = ((const float*)&a0)[e], x1 = ((const float*)&a1)[e];
            float m_a = fmaf(cw0[e], x_m2, fmaf(cw1[e], x_m1, fmaf(cw2[e], x0, cb4[e])));
            float v_a = m_a + x_m1; v_a = v_a > 0.f ? v_a : 0.f;
            s_m1 = fmaf(v_a, lw4[e], s_m1);
            float m_b = fmaf(cw0[e], x_m1, fmaf(cw1[e], x0, fmaf(cw2[e], x1, cb4[e])));
            float v_b = m_b + x0; v_b = v_b > 0.f ? v_b : 0.f;
            s_0 = fmaf(v_b, lw4[e], s_0);
        }
        #pragma unroll
        for (int off = 1; off <= 4; off <<= 1) {
            s_m1 += __shfl_xor(s_m1, off, 64);
            s_0  += __shfl_xor(s_0, off, 64);
        }
        if (dl == 0) {
            const int t0 = st * kTT + 2 * p;
            if (t0 > 0) atomicAdd(acc_g + (t0 - 1), s_m1);
            atomicAdd(acc_g + t0, s_0);
        }
        __syncthreads();                          // B2: wedge safe to overwrite
        a0 = n0; a1 = n1;
    }
    // final t = 2047 (needs h[2046], h[2047] from tile-7 edge; h[2048] = 0 pad)
    if (tid < 8) {
        float sacc = 0.f;
        #pragma unroll
        for (int e = 0; e < 4; e++) {
            float xm1 = tedge[1][dl][e];       // h[2046]
            float x0  = tedge[1][dl][4 + e];   // h[2047]
            float m = fmaf(cw0[e], xm1, fmaf(cw1[e], x0, cb4[e]));
            float v = m + x0; v = v > 0.f ? v : 0.f;
            sacc = fmaf(v, lw4[e], sacc);
        }
        #pragma unroll
        for (int off = 1; off <= 4; off <<= 1) sacc += __shfl_xor(sacc, off, 64);
        if (dl == 0) atomicAdd(acc_g + (kT - 1), sacc);
    }

    // ---- grid barrier (256 blocks, all resident; bounded spin -> no harness hang) ----
    __threadfence();
    __syncthreads();
    if (tid == 0) {
        __hip_atomic_fetch_add(counter, 1u, __ATOMIC_RELEASE, __HIP_MEMORY_SCOPE_AGENT);
        long long guard = 0;
        while (__hip_atomic_load(counter, __ATOMIC_ACQUIRE, __HIP_MEMORY_SCOPE_AGENT) < (unsigned)kNB) {
            __builtin_amdgcn_s_sleep(2);
            if (++guard > (3LL << 20)) break;   // ~100 ms safety valve
        }
    }
    __syncthreads();

    // ---- Phase B: scan -> al_s, banded MFMA attention from LDS-resident V ----
    const int lm = lane & 15, quad = lane >> 4;
    const float sig = sigma[h];
    const float lb = lin_b[0];

    float l0 = __hip_atomic_load(acc_g + 2 * tid,     __ATOMIC_RELAXED, __HIP_MEMORY_SCOPE_AGENT);
    float l1 = __hip_atomic_load(acc_g + 2 * tid + 1, __ATOMIC_RELAXED, __HIP_MEMORY_SCOPE_AGENT);
    float2 mv = ((const float2*)(mask + (size_t)b * kT))[tid];
    float aw0 = (1.f / (1.f + expf(-(l0 + lb)))) * mv.x;   // relu(sigmoid*1-0) == sigmoid
    float aw1 = (1.f / (1.f + expf(-(l1 + lb)))) * mv.y;

    const float p0 = aw0, p1v = aw0 + aw1;
    float sc = p1v;
    #pragma unroll
    for (int off = 1; off <= 32; off <<= 1) {
        float v = __shfl_up(sc, off, 64);
        sc = (lane >= off) ? sc + v : sc;
    }
    if (lane == 63) woff[wave] = sc;
    __syncthreads();
    if (tid == 0) {
        float run = 0.f;
        #pragma unroll
        for (int w = 0; w < 16; w++) { float x = woff[w]; woff[w] = run; run += x; }
        s_tot = run;
    }
    __syncthreads();
    const float tot = s_tot;
    const float scale = (tot != 0.f) ? ((float)target[b] / tot) : 0.f;
    const float basev = woff[wave] + (sc - p1v);
    {
        float c0 = (basev + p0) * scale;
        float c1 = (basev + p1v) * scale;
        float2 alv;
        alv.x = (mv.x > 0.f) ? c0 : 1.0e30f;
        alv.y = (mv.y > 0.f) ? c1 : 1.0e30f;
        ((float2*)al_s)[tid] = alv;
    }
    if (ds == 0 && h == 0) {
        if (tid == 0) out_tok[b] = tot;
        float2 oa; oa.x = aw0 * scale; oa.y = aw1 * scale;
        ((float2*)(out_alpha + (size_t)b * kT))[tid] = oa;
    }
    __syncthreads();

    // per-lane u: exact softmax max via binary search (al_s monotone)
    const int u_base = wave * 16;
    const float du = (float)(u_base + lm) + 0.5f;
    const float dusig = du * sig;
    int pos = 0;
    #pragma unroll
    for (int stp = 1024; stp >= 1; stp >>= 1) {
        int np = pos + stp;
        pos = (al_s[np - 1] < du) ? np : pos;
    }
    float d1 = (pos < kT) ? al_s[pos] - du : 3.0e30f;
    float d0 = (pos > 0) ? du - al_s[pos - 1] : 3.0e30f;
    float dmin = fminf(d0, d1);
    float ms = fminf(dmin, 1.0e4f) * sig;
    const float mu_pos = ms * ms;                    // = -max_score (>= 0)

    // wave band: |du - al| <= sqrt(dmax^2 + 21/sig^2)
    float dmax_l = fminf(dmin, 1.0e4f);
    #pragma unroll
    for (int off = 8; off >= 1; off >>= 1) dmax_l = fmaxf(dmax_l, __shfl_xor(dmax_l, off, 64));
    const float c21 = (sig > 1e-3f) ? 21.0f / (sig * sig) : 9.0e60f;
    const float bound = sqrtf(fmaf(dmax_l, dmax_l, c21));
    const float lo_b = (float)u_base + 0.5f - bound;
    const float hi_b = (float)u_base + 15.5f + bound;
    int p_lo = 0, p_hi = 0;
    #pragma unroll
    for (int stp = 1024; stp >= 1; stp >>= 1) {
        int n1 = p_lo + stp; p_lo = (al_s[n1 - 1] < lo_b) ? n1 : p_lo;
        int n2 = p_hi + stp; p_hi = (al_s[n2 - 1] < hi_b) ? n2 : p_hi;
    }
    const int ks_lo = p_lo >> 5;
    const int ks_end = (p_hi + 31) >> 5;

    float4v acc0 = (float4v)(0.f), acc1 = (float4v)(0.f);
    float lsum = 0.f;

    for (int kg = ks_lo; kg < ks_end; kg++) {
        const int kb = kg * 32;
        float alv[8];
        *(float4*)&alv[0] = *(const float4*)&al_s[kb + quad * 8];
        *(float4*)&alv[4] = *(const float4*)&al_s[kb + quad * 8 + 4];

        short8 afrag;
        #pragma unroll
        for (int j = 0; j < 8; j++) {
            float d = fmaf(-alv[j], sig, dusig);      // (du - al) * sig
            float e = __expf(fmaf(-d, d, mu_pos));    // exp(max - d^2) <= 1
            lsum += e;
            afrag[j] = f2bf(e);
        }
        short8 bf0 = *(const short8*)&bV[lm * kPitch + kb + quad * 8];
        short8 bf1 = *(const short8*)&bV[(16 + lm) * kPitch + kb + quad * 8];
        acc0 = __builtin_amdgcn_mfma_f32_16x16x32_bf16(afrag, bf0, acc0, 0, 0, 0);
        acc1 = __builtin_amdgcn_mfma_f32_16x16x32_bf16(afrag, bf1, acc1, 0, 0, 0);
    }

    // epilogue: reduce l across quads, normalize, direct store (disjoint)
    float lv = lsum;
    lv += __shfl_xor(lv, 16, 64);
    lv += __shfl_xor(lv, 32, 64);
    #pragma unroll
    for (int r = 0; r < 4; r++) {
        const int ur = quad * 4 + r;
        float rl = __shfl(lv, ur, 64);
        float linv = (rl > 1e-30f) ? 1.f / rl : 0.f;
        const int u = u_base + ur;
        if (u < kU) {
            float* dst = out_ac + ((size_t)(b * kU + u)) * kC + h * kDH + ds * kDW + lm;
            dst[0]  = acc0[r] * linv;
            dst[16] = acc1[r] * linv;
        }
    }
}

extern "C" void kernel_launch(void* const* d_in, const int* in_sizes, int n_in,
                              void* d_out, int out_size, void* d_ws, size_t ws_size,
                              hipStream_t stream) {
    const float* hid    = (const float*)d_in[0];
    const float* mask   = (const float*)d_in[1];
    const int*   tgt    = (const int*)d_in[2];
    // d_in[3] = max_token scalar (compile-time kU=250)
    const float* conv_w = (const float*)d_in[4];
    const float* conv_b = (const float*)d_in[5];
    const float* lin_w  = (const float*)d_in[6];
    const float* lin_b  = (const float*)d_in[7];
    const float* sigma  = (const float*)d_in[8];
    // d_in[9] = sigma_bias: constant over t -> cancels in softmax; unused.

    float* alpha_acc = (float*)d_ws;                           // [B*T] logit partials
    unsigned int* counter = (unsigned int*)((char*)d_ws + (size_t)kB * kT * 4);

    float* out_ac    = (float*)d_out;                          // [B, U, C]
    float* out_tok   = out_ac + (size_t)kB * kU * kC;          // [B]
    float* out_alpha = out_tok + kB;                           // [B, T]

    // zero the accumulators + grid-barrier counter (graph-capturable memset node)
    hipMemsetAsync(d_ws, 0, (size_t)kB * kT * 4 + 64, stream);
    fused_pif<<<dim3(kDS, kH, kB), 1024, 0, stream>>>(
        hid, mask, tgt, sigma, conv_w, conv_b, lin_w, lin_b,
        alpha_acc, counter, out_ac, out_tok, out_alpha);
}

// Round 2
// 157.005 us; speedup vs baseline: 1.5137x; 1.5137x over previous
//
#include <hip/hip_runtime.h>

namespace {
constexpr int kB = 16, kT = 2048, kC = 512, kH = 4, kU = 250, kDH = 128;
constexpr int kDS = 4;          // d-split blocks per (b,h)
constexpr int kDW = 32;         // d per block
constexpr int kTT = 256;        // t per staging tile
constexpr int kNST = kT / kTT;  // 8
constexpr int kPitch = 2056;    // V row pitch in shorts: dword stride 1028 == 4 mod 32 (2-way, free)
constexpr int kNB = kDS * kH * kB;  // 256 blocks == 1 per CU, all co-resident
}

typedef __attribute__((ext_vector_type(8))) short short8;
typedef __attribute__((ext_vector_type(4))) float float4v;

__device__ __forceinline__ short f2bf(float x) {
    union { float f; unsigned int u; } v; v.f = x;
    unsigned int r = (v.u + 0x7FFFu + ((v.u >> 16) & 1u)) >> 16;
    return (short)r;
}

// Single fused kernel. grid (ds=4, h=4, b=16) = 256 blocks x 1024 thr (1 block/CU).
// Phase A: stage own c-slice [cbase, cbase+32) x all T as bf16 V into LDS (hidden read
//   ONCE for the whole net) and compute the slice's f32 alpha-logit partials,
//   atomicAdd'ed into alpha_acc[b][t] (agent-scope atomics -> coherence point, no
//   L2 flushes needed).
// Grid barrier (cheap form): __syncthreads already drains vmcnt before s_barrier;
//   tid0 does ONE release fetch_add then RELAXED polls (no buffer_inv per poll --
//   round-1's ACQUIRE polls + per-thread threadfence caused an L2 wbl2/inv storm
//   that cost ~100us).
// Phase B: scan -> al_s, exact softmax max via binary search, banded chunk loop
//   with MFMA from LDS-resident V -- zero barriers.
__global__ __launch_bounds__(1024) void fused_pif(
    const float* __restrict__ hid, const float* __restrict__ mask,
    const int* __restrict__ target, const float* __restrict__ sigma,
    const float* __restrict__ conv_w, const float* __restrict__ conv_b,
    const float* __restrict__ lin_w, const float* __restrict__ lin_b,
    float* __restrict__ alpha_acc, unsigned int* __restrict__ counter,
    float* __restrict__ out_ac, float* __restrict__ out_tok, float* __restrict__ out_alpha)
{
    __shared__ unsigned short bV[kDW * kPitch];   // 131584 B: [d][t] bf16, all T
    __shared__ float al_s[kT];                    // 8 KB alignment
    __shared__ float wedge[2][16][8][8];          // 8 KB wave-edge f32 {a0,a1}, dbuf by st&1
    __shared__ float tedge[kNST][8][8];           // 2 KB tile-edge, one slot per tile
    __shared__ float woff[16];
    __shared__ float s_tot;

    const int ds = blockIdx.x, h = blockIdx.y, b = blockIdx.z;
    const int tid = threadIdx.x;
    const int wave = tid >> 6, lane = tid & 63;
    const int dl = tid & 7;          // c-quad within slice (4 c each)
    const int p  = tid >> 3;         // t-pair index within tile (0..127)
    const int pl = lane >> 3;        // p position within wave (0..7)
    const int cbase = h * kDH + ds * kDW;
    const int c0g = cbase + dl * 4;

    // ---- per-thread conv/linear weights for my 4 channels (f32, exact) ----
    float cw0[4], cw1[4], cw2[4], cb4[4], lw4[4];
    {
        float4 w0 = *(const float4*)(conv_w + c0g * 3);
        float4 w1 = *(const float4*)(conv_w + c0g * 3 + 4);
        float4 w2 = *(const float4*)(conv_w + c0g * 3 + 8);
        cw0[0] = w0.x; cw1[0] = w0.y; cw2[0] = w0.z;
        cw0[1] = w0.w; cw1[1] = w1.x; cw2[1] = w1.y;
        cw0[2] = w1.z; cw1[2] = w1.w; cw2[2] = w2.x;
        cw0[3] = w2.y; cw1[3] = w2.z; cw2[3] = w2.w;
        *(float4*)cb4 = *(const float4*)(conv_b + c0g);
        *(float4*)lw4 = *(const float4*)(lin_w + c0g);
    }
    float* acc_g = alpha_acc + (size_t)b * kT;
    const float* hrow = hid + (size_t)b * kT * kC + c0g;

    // ---- Phase A: stage V (bf16) + f32 conv/linear partials, tile by tile ----
    float4 a0, a1;
    {
        const float* s = hrow + (size_t)(2 * p) * kC;
        a0 = *(const float4*)s;
        a1 = *(const float4*)(s + kC);
    }
    for (int st = 0; st < kNST; st++) {
        // bf16 V into LDS (disjoint region per tile, never overwritten)
        #pragma unroll
        for (int e = 0; e < 4; e++) {
            unsigned int lo = (unsigned int)(unsigned short)f2bf(((const float*)&a0)[e]);
            unsigned int hi = (unsigned int)(unsigned short)f2bf(((const float*)&a1)[e]);
            *(unsigned int*)&bV[(dl * 4 + e) * kPitch + st * kTT + 2 * p] = lo | (hi << 16);
        }
        // publish edge rows (f32) for cross-wave / cross-tile conv neighbors
        if (pl == 7) {
            *(float4*)&wedge[st & 1][wave][dl][0] = a0;
            *(float4*)&wedge[st & 1][wave][dl][4] = a1;
            if (wave == 15) {
                *(float4*)&tedge[st][dl][0] = a0;
                *(float4*)&tedge[st][dl][4] = a1;
            }
        }
        // prefetch next tile before the barrier (latency hides behind conv)
        float4 n0 = a0, n1 = a1;
        if (st + 1 < kNST) {
            const float* s = hrow + (size_t)((st + 1) * kTT + 2 * p) * kC;
            n0 = *(const float4*)s;
            n1 = *(const float4*)(s + kC);
        }
        __syncthreads();                          // single barrier per tile

        // neighbors h[t0-2], h[t0-1] (t0 = st*256 + 2p)
        float pm2[4], pm1[4];
        #pragma unroll
        for (int e = 0; e < 4; e++) {
            pm2[e] = __shfl_up(((const float*)&a0)[e], 8, 64);
            pm1[e] = __shfl_up(((const float*)&a1)[e], 8, 64);
        }
        if (pl == 0) {
            if (wave > 0) {
                *(float4*)pm2 = *(const float4*)&wedge[st & 1][wave - 1][dl][0];
                *(float4*)pm1 = *(const float4*)&wedge[st & 1][wave - 1][dl][4];
            } else if (st > 0) {
                *(float4*)pm2 = *(const float4*)&tedge[st - 1][dl][0];
                *(float4*)pm1 = *(const float4*)&tedge[st - 1][dl][4];
            } else {
                pm2[0] = pm2[1] = pm2[2] = pm2[3] = 0.f;
                pm1[0] = pm1[1] = pm1[2] = pm1[3] = 0.f;
            }
        }
        // conv outputs at t0-1 and t0 (covers tile offsets -1..254; 255 done by next tile)
        float s_m1 = 0.f, s_0 = 0.f;
        #pragma unroll
        for (int e = 0; e < 4; e++) {
            float x_m2 = pm2[e], x_m1 = pm1[e];
            float x0 = ((const float*)&a0)[e], x1 = ((const float*)&a1)[e];
            float m_a = fmaf(cw0[e], x_m2, fmaf(cw1[e], x_m1, fmaf(cw2[e], x0, cb4[e])));
            float v_a = m_a + x_m1; v_a = v_a > 0.f ? v_a : 0.f;
            s_m1 = fmaf(v_a, lw4[e], s_m1);
            float m_b = fmaf(cw0[e], x_m1, fmaf(cw1[e], x0, fmaf(cw2[e], x1, cb4[e])));
            float v_b = m_b + x0; v_b = v_b > 0.f ? v_b : 0.f;
            s_0 = fmaf(v_b, lw4[e], s_0);
        }
        #pragma unroll
        for (int off = 1; off <= 4; off <<= 1) {
            s_m1 += __shfl_xor(s_m1, off, 64);
            s_0  += __shfl_xor(s_0, off, 64);
        }
        if (dl == 0) {
            const int t0 = st * kTT + 2 * p;
            if (t0 > 0) atomicAdd(acc_g + (t0 - 1), s_m1);
            atomicAdd(acc_g + t0, s_0);
        }
        a0 = n0; a1 = n1;
    }
    // final t = 2047 (needs h[2046], h[2047] from tile-7 edge; h[2048] = 0 pad)
    if (tid < 8) {
        float sacc = 0.f;
        #pragma unroll
        for (int e = 0; e < 4; e++) {
            float xm1 = tedge[kNST - 1][dl][e];       // h[2046]
            float x0  = tedge[kNST - 1][dl][4 + e];   // h[2047]
            float m = fmaf(cw0[e], xm1, fmaf(cw1[e], x0, cb4[e]));
            float v = m + x0; v = v > 0.f ? v : 0.f;
            sacc = fmaf(v, lw4[e], sacc);
        }
        #pragma unroll
        for (int off = 1; off <= 4; off <<= 1) sacc += __shfl_xor(sacc, off, 64);
        if (dl == 0) atomicAdd(acc_g + (kT - 1), sacc);
    }

    // ---- grid barrier (256 blocks, all resident; bounded spin -> no harness hang) ----
    // __syncthreads drains vmcnt(0) before s_barrier => this block's atomicAdds
    // (agent-scope, performed at coherence point) are globally visible.
    __syncthreads();
    if (tid == 0) {
        __hip_atomic_fetch_add(counter, 1u, __ATOMIC_RELEASE, __HIP_MEMORY_SCOPE_AGENT);
        long long guard = 0;
        // RELAXED polls: no per-iteration L2 invalidate (round-1 regression cause)
        while (__hip_atomic_load(counter, __ATOMIC_RELAXED, __HIP_MEMORY_SCOPE_AGENT) < (unsigned)kNB) {
            __builtin_amdgcn_s_sleep(4);
            if (++guard > (3LL << 20)) break;   // safety valve
        }
    }
    __syncthreads();

    // ---- Phase B: scan -> al_s, banded MFMA attention from LDS-resident V ----
    const int lm = lane & 15, quad = lane >> 4;
    const float sig = sigma[h];
    const float lb = lin_b[0];

    // cache-bypassing (agent-scope) loads: always coherent with the RMWs above
    float l0 = __hip_atomic_load(acc_g + 2 * tid,     __ATOMIC_RELAXED, __HIP_MEMORY_SCOPE_AGENT);
    float l1 = __hip_atomic_load(acc_g + 2 * tid + 1, __ATOMIC_RELAXED, __HIP_MEMORY_SCOPE_AGENT);
    float2 mv = ((const float2*)(mask + (size_t)b * kT))[tid];
    float aw0 = (1.f / (1.f + expf(-(l0 + lb)))) * mv.x;   // relu(sigmoid*1-0) == sigmoid
    float aw1 = (1.f / (1.f + expf(-(l1 + lb)))) * mv.y;

    const float p0 = aw0, p1v = aw0 + aw1;
    float sc = p1v;
    #pragma unroll
    for (int off = 1; off <= 32; off <<= 1) {
        float v = __shfl_up(sc, off, 64);
        sc = (lane >= off) ? sc + v : sc;
    }
    if (lane == 63) woff[wave] = sc;
    __syncthreads();
    if (tid == 0) {
        float run = 0.f;
        #pragma unroll
        for (int w = 0; w < 16; w++) { float x = woff[w]; woff[w] = run; run += x; }
        s_tot = run;
    }
    __syncthreads();
    const float tot = s_tot;
    const float scale = (tot != 0.f) ? ((float)target[b] / tot) : 0.f;
    const float basev = woff[wave] + (sc - p1v);
    {
        float c0 = (basev + p0) * scale;
        float c1 = (basev + p1v) * scale;
        float2 alv;
        alv.x = (mv.x > 0.f) ? c0 : 1.0e30f;
        alv.y = (mv.y > 0.f) ? c1 : 1.0e30f;
        ((float2*)al_s)[tid] = alv;
    }
    if (ds == 0 && h == 0) {
        if (tid == 0) out_tok[b] = tot;
        float2 oa; oa.x = aw0 * scale; oa.y = aw1 * scale;
        ((float2*)(out_alpha + (size_t)b * kT))[tid] = oa;
    }
    __syncthreads();

    // per-lane u: exact softmax max via binary search (al_s monotone)
    const int u_base = wave * 16;
    const float du = (float)(u_base + lm) + 0.5f;
    const float dusig = du * sig;
    int pos = 0;
    #pragma unroll
    for (int stp = 1024; stp >= 1; stp >>= 1) {
        int np = pos + stp;
        pos = (al_s[np - 1] < du) ? np : pos;
    }
    float d1 = (pos < kT) ? al_s[pos] - du : 3.0e30f;
    float d0 = (pos > 0) ? du - al_s[pos - 1] : 3.0e30f;
    float dmin = fminf(d0, d1);
    float ms = fminf(dmin, 1.0e4f) * sig;
    const float mu_pos = ms * ms;                    // = -max_score (>= 0)

    // wave band: |du - al| <= sqrt(dmax^2 + 21/sig^2)
    float dmax_l = fminf(dmin, 1.0e4f);
    #pragma unroll
    for (int off = 8; off >= 1; off >>= 1) dmax_l = fmaxf(dmax_l, __shfl_xor(dmax_l, off, 64));
    const float c21 = (sig > 1e-3f) ? 21.0f / (sig * sig) : 9.0e60f;
    const float bound = sqrtf(fmaf(dmax_l, dmax_l, c21));
    const float lo_b = (float)u_base + 0.5f - bound;
    const float hi_b = (float)u_base + 15.5f + bound;
    int p_lo = 0, p_hi = 0;
    #pragma unroll
    for (int stp = 1024; stp >= 1; stp >>= 1) {
        int n1 = p_lo + stp; p_lo = (al_s[n1 - 1] < lo_b) ? n1 : p_lo;
        int n2 = p_hi + stp; p_hi = (al_s[n2 - 1] < hi_b) ? n2 : p_hi;
    }
    const int ks_lo = p_lo >> 5;
    const int ks_end = (p_hi + 31) >> 5;

    float4v acc0 = (float4v)(0.f), acc1 = (float4v)(0.f);
    float lsum = 0.f;

    for (int kg = ks_lo; kg < ks_end; kg++) {
        const int kb = kg * 32;
        float alv[8];
        *(float4*)&alv[0] = *(const float4*)&al_s[kb + quad * 8];
        *(float4*)&alv[4] = *(const float4*)&al_s[kb + quad * 8 + 4];

        short8 afrag;
        #pragma unroll
        for (int j = 0; j < 8; j++) {
            float d = fmaf(-alv[j], sig, dusig);      // (du - al) * sig
            float e = __expf(fmaf(-d, d, mu_pos));    // exp(max - d^2) <= 1
            lsum += e;
            afrag[j] = f2bf(e);
        }
        short8 bf0 = *(const short8*)&bV[lm * kPitch + kb + quad * 8];
        short8 bf1 = *(const short8*)&bV[(16 + lm) * kPitch + kb + quad * 8];
        acc0 = __builtin_amdgcn_mfma_f32_16x16x32_bf16(afrag, bf0, acc0, 0, 0, 0);
        acc1 = __builtin_amdgcn_mfma_f32_16x16x32_bf16(afrag, bf1, acc1, 0, 0, 0);
    }

    // epilogue: reduce l across quads, normalize, direct store (disjoint)
    float lv = lsum;
    lv += __shfl_xor(lv, 16, 64);
    lv += __shfl_xor(lv, 32, 64);
    #pragma unroll
    for (int r = 0; r < 4; r++) {
        const int ur = quad * 4 + r;
        float rl = __shfl(lv, ur, 64);
        float linv = (rl > 1e-30f) ? 1.f / rl : 0.f;
        const int u = u_base + ur;
        if (u < kU) {
            float* dst = out_ac + ((size_t)(b * kU + u)) * kC + h * kDH + ds * kDW + lm;
            dst[0]  = acc0[r] * linv;
            dst[16] = acc1[r] * linv;
        }
    }
}

extern "C" void kernel_launch(void* const* d_in, const int* in_sizes, int n_in,
                              void* d_out, int out_size, void* d_ws, size_t ws_size,
                              hipStream_t stream) {
    const float* hid    = (const float*)d_in[0];
    const float* mask   = (const float*)d_in[1];
    const int*   tgt    = (const int*)d_in[2];
    // d_in[3] = max_token scalar (compile-time kU=250)
    const float* conv_w = (const float*)d_in[4];
    const float* conv_b = (const float*)d_in[5];
    const float* lin_w  = (const float*)d_in[6];
    const float* lin_b  = (const float*)d_in[7];
    const float* sigma  = (const float*)d_in[8];
    // d_in[9] = sigma_bias: constant over t -> cancels in softmax; unused.

    float* alpha_acc = (float*)d_ws;                           // [B*T] logit partials
    unsigned int* counter = (unsigned int*)((char*)d_ws + (size_t)kB * kT * 4);

    float* out_ac    = (float*)d_out;                          // [B, U, C]
    float* out_tok   = out_ac + (size_t)kB * kU * kC;          // [B]
    float* out_alpha = out_tok + kB;                           // [B, T]

    // zero the accumulators + grid-barrier counter (graph-capturable memset node)
    hipMemsetAsync(d_ws, 0, (size_t)kB * kT * 4 + 64, stream);
    fused_pif<<<dim3(kDS, kH, kB), 1024, 0, stream>>>(
        hid, mask, tgt, sigma, conv_w, conv_b, lin_w, lin_b,
        alpha_acc, counter, out_ac, out_tok, out_alpha);
}

// Round 4
// 147.357 us; speedup vs baseline: 1.6128x; 1.0655x over previous
//
#include <hip/hip_runtime.h>

namespace {
constexpr int kB = 16, kT = 2048, kC = 512, kH = 4, kU = 250, kDH = 128;
constexpr int kDS = 4;          // d-split blocks per (b,h)
constexpr int kDW = 32;         // d per block
constexpr int kPitch = 2056;    // V row pitch in shorts (16B-aligned rows, balanced banks)
constexpr int kNB = kDS * kH * kB;  // 256 blocks == 1 per CU, all co-resident
constexpr int kNS = 16;         // alpha partial slices (= blocks per b)
}

typedef __attribute__((ext_vector_type(8))) short short8;
typedef __attribute__((ext_vector_type(4))) float float4v;

__device__ __forceinline__ short f2bf(float x) {
    union { float f; unsigned int u; } v; v.f = x;
    unsigned int r = (v.u + 0x7FFFu + ((v.u >> 16) & 1u)) >> 16;
    return (short)r;
}

// Single fused kernel. grid (ds=4, h=4, b=16) = 256 blocks x 1024 thr (1 block/CU).
// Phase A (barrier-free): each WAVE owns t-range [w*128, w*128+128). 8 passes of
//   2 t-rows/thread; conv neighbors via shfl_up (interior), prev-pass regs via shfl
//   (pass boundary), tiny global halo load (wave boundary). bf16 V -> LDS; f32
//   conv/linear partial -> private row part[slice][b][t] via relaxed agent-scope
//   atomic STORES (no RMW contention, no zeroing; round-2's 524K contended
//   atomicAdds + per-tile barrier drains were the stall source).
// Grid barrier: one release fetch_add + RELAXED polls (round-1 lesson: ACQUIRE
//   polls + per-thread threadfence caused an L2 wbl2/inv storm costing ~100us).
// Phase B: sum 16 slices (agent loads) -> sigmoid -> scan -> al_s; exact softmax
//   max via binary search; banded chunk loop with MFMA from LDS-resident V.
__global__ __launch_bounds__(1024) void fused_pif(
    const float* __restrict__ hid, const float* __restrict__ mask,
    const int* __restrict__ target, const float* __restrict__ sigma,
    const float* __restrict__ conv_w, const float* __restrict__ conv_b,
    const float* __restrict__ lin_w, const float* __restrict__ lin_b,
    float* __restrict__ part, unsigned int* __restrict__ counter,
    float* __restrict__ out_ac, float* __restrict__ out_tok, float* __restrict__ out_alpha)
{
    __shared__ unsigned short bV[kDW * kPitch];   // 131584 B: [d][t] bf16, all T
    __shared__ float al_s[kT];                    // 8 KB
    __shared__ float woff[16];
    __shared__ float s_tot;

    const int ds = blockIdx.x, h = blockIdx.y, b = blockIdx.z;
    const int tid = threadIdx.x;
    const int wave = tid >> 6, lane = tid & 63;
    const int dl = lane & 7;         // c-quad within slice (4 c each)
    const int q  = lane >> 3;        // t-pair within pass (0..7)
    const int cbase = h * kDH + ds * kDW;
    const int c0g = cbase + dl * 4;
    const int slice = h * kDS + ds;

    // ---- per-thread conv/linear weights for my 4 channels (f32, exact) ----
    float cw0[4], cw1[4], cw2[4], cb4[4], lw4[4];
    {
        float4 w0 = *(const float4*)(conv_w + c0g * 3);
        float4 w1 = *(const float4*)(conv_w + c0g * 3 + 4);
        float4 w2 = *(const float4*)(conv_w + c0g * 3 + 8);
        cw0[0] = w0.x; cw1[0] = w0.y; cw2[0] = w0.z;
        cw0[1] = w0.w; cw1[1] = w1.x; cw2[1] = w1.y;
        cw0[2] = w1.z; cw1[2] = w1.w; cw2[2] = w2.x;
        cw0[3] = w2.y; cw1[3] = w2.z; cw2[3] = w2.w;
        *(float4*)cb4 = *(const float4*)(conv_b + c0g);
        *(float4*)lw4 = *(const float4*)(lin_w + c0g);
    }
    float* pp = part + ((size_t)slice * kB + b) * kT;
    const float* hrow = hid + (size_t)b * kT * kC + c0g;
    const int wbase = wave * 128;

    // ---- Phase A: barrier-free staging + conv partials ----
    float4 A0[4], A1[4], B0[4], B1[4];
    float4 h2, h1;
    h2.x = h2.y = h2.z = h2.w = 0.f;
    h1 = h2;
    if (q == 0 && wave > 0) {                     // wave-boundary halo (needed first)
        const float* s = hrow + (size_t)(wbase - 2) * kC;
        h2 = *(const float4*)s;
        h1 = *(const float4*)(s + kC);
    }
    #pragma unroll
    for (int k = 0; k < 4; k++) {                 // first-half loads (8 in flight)
        const float* s = hrow + (size_t)(wbase + k * 16 + 2 * q) * kC;
        A0[k] = *(const float4*)s;
        A1[k] = *(const float4*)(s + kC);
    }
    float4 Lp0, Lp1;                              // previous pass's pair (for q==0)
    Lp0 = h2; Lp1 = h1;

    // PROC(kk): process pass kk with pair (Ax=h[t0], Ay=h[t0+1]), t0=wbase+16kk+2q
    #define PROC(kk, Ax, Ay)  {                                                  \
        const int t0 = wbase + (kk) * 16 + 2 * q;                                \
        float pm2[4], pm1[4];                                                    \
        _Pragma("unroll")                                                        \
        for (int e = 0; e < 4; e++) {                                            \
            float c2, c1v;                                                       \
            if ((kk) == 0) { c2 = ((float*)&h2)[e]; c1v = ((float*)&h1)[e]; }    \
            else {                                                               \
                c2  = __shfl(((float*)&Lp0)[e], 56 + dl, 64);                    \
                c1v = __shfl(((float*)&Lp1)[e], 56 + dl, 64);                    \
            }                                                                    \
            float s2 = __shfl_up(((float*)&Ax)[e], 8, 64);                       \
            float s1 = __shfl_up(((float*)&Ay)[e], 8, 64);                       \
            pm2[e] = (q == 0) ? c2  : s2;                                        \
            pm1[e] = (q == 0) ? c1v : s1;                                        \
        }                                                                        \
        _Pragma("unroll")                                                        \
        for (int e = 0; e < 4; e++) {                                            \
            unsigned int lo = (unsigned int)(unsigned short)f2bf(((float*)&Ax)[e]); \
            unsigned int hi = (unsigned int)(unsigned short)f2bf(((float*)&Ay)[e]); \
            *(unsigned int*)&bV[(dl * 4 + e) * kPitch + t0] = lo | (hi << 16);   \
        }                                                                        \
        float s_m1 = 0.f, s_0 = 0.f;                                             \
        _Pragma("unroll")                                                        \
        for (int e = 0; e < 4; e++) {                                            \
            float x_m2 = pm2[e], x_m1 = pm1[e];                                  \
            float x0 = ((float*)&Ax)[e], x1 = ((float*)&Ay)[e];                  \
            float m_a = fmaf(cw0[e], x_m2, fmaf(cw1[e], x_m1, fmaf(cw2[e], x0, cb4[e]))); \
            float v_a = m_a + x_m1; v_a = v_a > 0.f ? v_a : 0.f;                 \
            s_m1 = fmaf(v_a, lw4[e], s_m1);                                      \
            float m_b = fmaf(cw0[e], x_m1, fmaf(cw1[e], x0, fmaf(cw2[e], x1, cb4[e]))); \
            float v_b = m_b + x0; v_b = v_b > 0.f ? v_b : 0.f;                   \
            s_0 = fmaf(v_b, lw4[e], s_0);                                        \
        }                                                                        \
        _Pragma("unroll")                                                        \
        for (int off = 1; off <= 4; off <<= 1) {                                 \
            s_m1 += __shfl_xor(s_m1, off, 64);                                   \
            s_0  += __shfl_xor(s_0, off, 64);                                    \
        }                                                                        \
        if (dl == 0) {                                                           \
            if (t0 > 0) __hip_atomic_store(pp + (t0 - 1), s_m1,                  \
                            __ATOMIC_RELAXED, __HIP_MEMORY_SCOPE_AGENT);         \
            __hip_atomic_store(pp + t0, s_0,                                     \
                            __ATOMIC_RELAXED, __HIP_MEMORY_SCOPE_AGENT);         \
        }                                                                        \
        Lp0 = Ax; Lp1 = Ay; }

    PROC(0, A0[0], A1[0])
    #pragma unroll
    for (int k = 0; k < 4; k++) {                 // second-half loads (8 in flight)
        const float* s = hrow + (size_t)(wbase + 64 + k * 16 + 2 * q) * kC;
        B0[k] = *(const float4*)s;
        B1[k] = *(const float4*)(s + kC);
    }
    PROC(1, A0[1], A1[1])
    PROC(2, A0[2], A1[2])
    PROC(3, A0[3], A1[3])
    PROC(4, B0[0], B1[0])
    PROC(5, B0[1], B1[1])
    PROC(6, B0[2], B1[2])
    PROC(7, B0[3], B1[3])
    #undef PROC

    // final t = 2047 (conv window h[2046], h[2047], 0-pad); Lp holds pass-7 pair
    if (wave == 15 && q == 7) {
        float sacc = 0.f;
        #pragma unroll
        for (int e = 0; e < 4; e++) {
            float xm1 = ((float*)&Lp0)[e];   // h[2046]
            float x0  = ((float*)&Lp1)[e];   // h[2047]
            float m = fmaf(cw0[e], xm1, fmaf(cw1[e], x0, cb4[e]));
            float v = m + x0; v = v > 0.f ? v : 0.f;
            sacc = fmaf(v, lw4[e], sacc);
        }
        #pragma unroll
        for (int off = 1; off <= 4; off <<= 1) sacc += __shfl_xor(sacc, off, 64);
        if (dl == 0) __hip_atomic_store(pp + (kT - 1), sacc,
                         __ATOMIC_RELAXED, __HIP_MEMORY_SCOPE_AGENT);
    }

    // ---- grid barrier (256 blocks, all resident; bounded spin) ----
    // __syncthreads drains vmcnt(0) => this block's agent-scope stores are visible.
    __syncthreads();
    if (tid == 0) {
        __hip_atomic_fetch_add(counter, 1u, __ATOMIC_RELEASE, __HIP_MEMORY_SCOPE_AGENT);
        long long guard = 0;
        while (__hip_atomic_load(counter, __ATOMIC_RELAXED, __HIP_MEMORY_SCOPE_AGENT) < (unsigned)kNB) {
            __builtin_amdgcn_s_sleep(2);
            if (++guard > (3LL << 20)) break;   // safety valve
        }
    }
    __syncthreads();

    // ---- Phase B: sum slices -> sigmoid -> scan -> al_s -> banded MFMA ----
    const int lm = lane & 15, quad = lane >> 4;
    const float sig = sigma[h];
    const float lb = lin_b[0];

    float l0 = 0.f, l1 = 0.f;
    #pragma unroll
    for (int s = 0; s < kNS; s++) {               // 16 independent 8-B agent loads
        unsigned long long uv = __hip_atomic_load(
            (const unsigned long long*)(part + ((size_t)s * kB + b) * kT + 2 * tid),
            __ATOMIC_RELAXED, __HIP_MEMORY_SCOPE_AGENT);
        union { unsigned long long u; float2 f; } cv; cv.u = uv;
        l0 += cv.f.x; l1 += cv.f.y;
    }
    float2 mv = ((const float2*)(mask + (size_t)b * kT))[tid];
    float aw0 = (1.f / (1.f + expf(-(l0 + lb)))) * mv.x;   // relu(sigmoid*1-0) == sigmoid
    float aw1 = (1.f / (1.f + expf(-(l1 + lb)))) * mv.y;

    const float p0 = aw0, p1v = aw0 + aw1;
    float sc = p1v;
    #pragma unroll
    for (int off = 1; off <= 32; off <<= 1) {
        float v = __shfl_up(sc, off, 64);
        sc = (lane >= off) ? sc + v : sc;
    }
    if (lane == 63) woff[wave] = sc;
    __syncthreads();
    if (tid == 0) {
        float run = 0.f;
        #pragma unroll
        for (int w = 0; w < 16; w++) { float x = woff[w]; woff[w] = run; run += x; }
        s_tot = run;
    }
    __syncthreads();
    const float tot = s_tot;
    const float scale = (tot != 0.f) ? ((float)target[b] / tot) : 0.f;
    const float basev = woff[wave] + (sc - p1v);
    {
        float c0 = (basev + p0) * scale;
        float c1 = (basev + p1v) * scale;
        float2 alv;
        alv.x = (mv.x > 0.f) ? c0 : 1.0e30f;
        alv.y = (mv.y > 0.f) ? c1 : 1.0e30f;
        ((float2*)al_s)[tid] = alv;
    }
    if (ds == 0 && h == 0) {
        if (tid == 0) out_tok[b] = tot;
        float2 oa; oa.x = aw0 * scale; oa.y = aw1 * scale;
        ((float2*)(out_alpha + (size_t)b * kT))[tid] = oa;
    }
    __syncthreads();

    // per-lane u: exact softmax max via binary search (al_s monotone)
    const int u_base = wave * 16;
    const float du = (float)(u_base + lm) + 0.5f;
    const float dusig = du * sig;
    int pos = 0;
    #pragma unroll
    for (int stp = 1024; stp >= 1; stp >>= 1) {
        int np = pos + stp;
        pos = (al_s[np - 1] < du) ? np : pos;
    }
    float d1 = (pos < kT) ? al_s[pos] - du : 3.0e30f;
    float d0 = (pos > 0) ? du - al_s[pos - 1] : 3.0e30f;
    float dmin = fminf(d0, d1);
    float ms = fminf(dmin, 1.0e4f) * sig;
    const float mu_pos = ms * ms;                    // = -max_score (>= 0)

    // wave band: |du - al| <= sqrt(dmax^2 + 21/sig^2)
    float dmax_l = fminf(dmin, 1.0e4f);
    #pragma unroll
    for (int off = 8; off >= 1; off >>= 1) dmax_l = fmaxf(dmax_l, __shfl_xor(dmax_l, off, 64));
    const float c21 = (sig > 1e-3f) ? 21.0f / (sig * sig) : 9.0e60f;
    const float bound = sqrtf(fmaf(dmax_l, dmax_l, c21));
    const float lo_b = (float)u_base + 0.5f - bound;
    const float hi_b = (float)u_base + 15.5f + bound;
    int p_lo = 0, p_hi = 0;
    #pragma unroll
    for (int stp = 1024; stp >= 1; stp >>= 1) {
        int n1 = p_lo + stp; p_lo = (al_s[n1 - 1] < lo_b) ? n1 : p_lo;
        int n2 = p_hi + stp; p_hi = (al_s[n2 - 1] < hi_b) ? n2 : p_hi;
    }
    const int ks_lo = p_lo >> 5;
    const int ks_end = (p_hi + 31) >> 5;

    float4v acc0 = (float4v)(0.f), acc1 = (float4v)(0.f);
    float lsum = 0.f;

    for (int kg = ks_lo; kg < ks_end; kg++) {
        const int kb = kg * 32;
        float alv[8];
        *(float4*)&alv[0] = *(const float4*)&al_s[kb + quad * 8];
        *(float4*)&alv[4] = *(const float4*)&al_s[kb + quad * 8 + 4];

        short8 afrag;
        #pragma unroll
        for (int j = 0; j < 8; j++) {
            float d = fmaf(-alv[j], sig, dusig);      // (du - al) * sig
            float e = __expf(fmaf(-d, d, mu_pos));    // exp(max - d^2) <= 1
            lsum += e;
            afrag[j] = f2bf(e);
        }
        short8 bf0 = *(const short8*)&bV[lm * kPitch + kb + quad * 8];
        short8 bf1 = *(const short8*)&bV[(16 + lm) * kPitch + kb + quad * 8];
        acc0 = __builtin_amdgcn_mfma_f32_16x16x32_bf16(afrag, bf0, acc0, 0, 0, 0);
        acc1 = __builtin_amdgcn_mfma_f32_16x16x32_bf16(afrag, bf1, acc1, 0, 0, 0);
    }

    // epilogue: reduce l across quads, normalize, direct store (disjoint)
    float lv = lsum;
    lv += __shfl_xor(lv, 16, 64);
    lv += __shfl_xor(lv, 32, 64);
    #pragma unroll
    for (int r = 0; r < 4; r++) {
        const int ur = quad * 4 + r;
        float rl = __shfl(lv, ur, 64);
        float linv = (rl > 1e-30f) ? 1.f / rl : 0.f;
        const int u = u_base + ur;
        if (u < kU) {
            float* dst = out_ac + ((size_t)(b * kU + u)) * kC + h * kDH + ds * kDW + lm;
            dst[0]  = acc0[r] * linv;
            dst[16] = acc1[r] * linv;
        }
    }
}

extern "C" void kernel_launch(void* const* d_in, const int* in_sizes, int n_in,
                              void* d_out, int out_size, void* d_ws, size_t ws_size,
                              hipStream_t stream) {
    const float* hid    = (const float*)d_in[0];
    const float* mask   = (const float*)d_in[1];
    const int*   tgt    = (const int*)d_in[2];
    // d_in[3] = max_token scalar (compile-time kU=250)
    const float* conv_w = (const float*)d_in[4];
    const float* conv_b = (const float*)d_in[5];
    const float* lin_w  = (const float*)d_in[6];
    const float* lin_b  = (const float*)d_in[7];
    const float* sigma  = (const float*)d_in[8];
    // d_in[9] = sigma_bias: constant over t -> cancels in softmax; unused.

    unsigned int* counter = (unsigned int*)d_ws;               // 256 B (zeroed)
    float* part = (float*)((char*)d_ws + 256);                 // [16][B][T] partials (fully overwritten)

    float* out_ac    = (float*)d_out;                          // [B, U, C]
    float* out_tok   = out_ac + (size_t)kB * kU * kC;          // [B]
    float* out_alpha = out_tok + kB;                           // [B, T]

    // zero only the grid-barrier counter
    hipMemsetAsync(d_ws, 0, 256, stream);
    fused_pif<<<dim3(kDS, kH, kB), 1024, 0, stream>>>(
        hid, mask, tgt, sigma, conv_w, conv_b, lin_w, lin_b,
        part, counter, out_ac, out_tok, out_alpha);
}

// Round 5
// 145.030 us; speedup vs baseline: 1.6387x; 1.0160x over previous
//
#include <hip/hip_runtime.h>

namespace {
constexpr int kB = 16, kT = 2048, kC = 512, kH = 4, kU = 250, kDH = 128;
constexpr int kDS = 4;          // d-split blocks per (b,h)
constexpr int kDW = 32;         // d per block
constexpr int kPitch = 2056;    // V row pitch in shorts (16B-aligned rows)
constexpr int kNB = kDS * kH * kB;  // 256 blocks == 1 per CU, all co-resident
}

typedef __attribute__((ext_vector_type(8))) short short8;
typedef __attribute__((ext_vector_type(4))) float float4v;

__device__ __forceinline__ short f2bf(float x) {
    union { float f; unsigned int u; } v; v.f = x;
    unsigned int r = (v.u + 0x7FFFu + ((v.u >> 16) & 1u)) >> 16;
    return (short)r;
}
// packed f32x2 -> bf16x2 (RNE), single VALU op; lo = src0, hi = src1
__device__ __forceinline__ unsigned int pk_bf16(float lo, float hi) {
    unsigned int r;
    asm volatile("v_cvt_pk_bf16_f32 %0, %1, %2" : "=v"(r) : "v"(lo), "v"(hi));
    return r;
}
__device__ __forceinline__ float exp2_fast(float x) {   // 2^x, raw v_exp
    float r;
    asm volatile("v_exp_f32 %0, %1" : "=v"(r) : "v"(x));
    return r;
}

// Single fused kernel. grid (ds=4, h=4, b=16) = 256 blocks x 1024 thr (1 block/CU).
// Phase A (barrier-free): wave-owned 128-t ranges; conv neighbors via shfl/regs/
//   tiny halo load; bf16 V -> LDS via v_cvt_pk_bf16_f32. Conv/linear partials ->
//   LDS scratch (al_s reused), then ONE coalesced burst of hardware-fp atomicAdds
//   into summed part[b][t] (round-4's 524K scattered 4-B uncached stores + 33 MB
//   uncached slice re-reads were ~30us of coherence-point machinery; now 2048
//   coalesced RMWs/block + one 8-B uncached read/thread).
// Grid barrier: one release fetch_add + RELAXED polls (round-1 lesson).
// Phase B: one part load -> sigmoid -> scan -> al_s; exact softmax max via binary
//   search; banded chunk loop (log2-domain exp) with MFMA from LDS-resident V.
__global__ __launch_bounds__(1024) void fused_pif(
    const float* __restrict__ hid, const float* __restrict__ mask,
    const int* __restrict__ target, const float* __restrict__ sigma,
    const float* __restrict__ conv_w, const float* __restrict__ conv_b,
    const float* __restrict__ lin_w, const float* __restrict__ lin_b,
    float* __restrict__ part, unsigned int* __restrict__ counter,
    float* __restrict__ out_ac, float* __restrict__ out_tok, float* __restrict__ out_alpha)
{
    __shared__ unsigned short bV[kDW * kPitch];   // 131584 B: [d][t] bf16, all T
    __shared__ float al_s[kT];                    // 8 KB; Phase A: partial scratch
    __shared__ float woff[16];
    __shared__ float s_tot;

    const int ds = blockIdx.x, h = blockIdx.y, b = blockIdx.z;
    const int tid = threadIdx.x;
    const int wave = tid >> 6, lane = tid & 63;
    const int dl = lane & 7;         // c-quad within slice (4 c each)
    const int q  = lane >> 3;        // t-pair within pass (0..7)
    const int cbase = h * kDH + ds * kDW;
    const int c0g = cbase + dl * 4;

    // ---- per-thread conv/linear weights for my 4 channels (f32, exact) ----
    float cw0[4], cw1[4], cw2[4], cb4[4], lw4[4];
    {
        float4 w0 = *(const float4*)(conv_w + c0g * 3);
        float4 w1 = *(const float4*)(conv_w + c0g * 3 + 4);
        float4 w2 = *(const float4*)(conv_w + c0g * 3 + 8);
        cw0[0] = w0.x; cw1[0] = w0.y; cw2[0] = w0.z;
        cw0[1] = w0.w; cw1[1] = w1.x; cw2[1] = w1.y;
        cw0[2] = w1.z; cw1[2] = w1.w; cw2[2] = w2.x;
        cw0[3] = w2.y; cw1[3] = w2.z; cw2[3] = w2.w;
        *(float4*)cb4 = *(const float4*)(conv_b + c0g);
        *(float4*)lw4 = *(const float4*)(lin_w + c0g);
    }
    float* pacc = part + (size_t)b * kT;
    const float* hrow = hid + (size_t)b * kT * kC + c0g;
    const int wbase = wave * 128;

    // ---- Phase A: barrier-free staging + conv partials (depth-3 load rotation) ----
    float4 h2, h1;
    h2.x = h2.y = h2.z = h2.w = 0.f;
    h1 = h2;
    if (q == 0 && wave > 0) {                     // wave-boundary halo
        const float* s = hrow + (size_t)(wbase - 2) * kC;
        h2 = *(const float4*)s;
        h1 = *(const float4*)(s + kC);
    }
    float4 xa0, xa1, xb0, xb1, xc0, xc1;
    #define LOADP(X, Y, kk) { const float* s_ = hrow + (size_t)(wbase + (kk) * 16 + 2 * q) * kC; \
                              X = *(const float4*)s_; Y = *(const float4*)(s_ + kC); }
    LOADP(xa0, xa1, 0)
    LOADP(xb0, xb1, 1)
    LOADP(xc0, xc1, 2)
    float4 Lp0, Lp1;                              // previous pass's pair (for q==0)
    Lp0 = h2; Lp1 = h1;

    // PROC(kk): process pass kk with pair (Ax=h[t0], Ay=h[t0+1]), t0=wbase+16kk+2q
    #define PROC(kk, Ax, Ay)  {                                                  \
        const int t0 = wbase + (kk) * 16 + 2 * q;                                \
        float pm2[4], pm1[4];                                                    \
        _Pragma("unroll")                                                        \
        for (int e = 0; e < 4; e++) {                                            \
            float c2, c1v;                                                       \
            if ((kk) == 0) { c2 = ((float*)&h2)[e]; c1v = ((float*)&h1)[e]; }    \
            else {                                                               \
                c2  = __shfl(((float*)&Lp0)[e], 56 + dl, 64);                    \
                c1v = __shfl(((float*)&Lp1)[e], 56 + dl, 64);                    \
            }                                                                    \
            float s2 = __shfl_up(((float*)&Ax)[e], 8, 64);                       \
            float s1 = __shfl_up(((float*)&Ay)[e], 8, 64);                       \
            pm2[e] = (q == 0) ? c2  : s2;                                        \
            pm1[e] = (q == 0) ? c1v : s1;                                        \
        }                                                                        \
        _Pragma("unroll")                                                        \
        for (int e = 0; e < 4; e++) {                                            \
            unsigned int w_ = pk_bf16(((float*)&Ax)[e], ((float*)&Ay)[e]);       \
            *(unsigned int*)&bV[(dl * 4 + e) * kPitch + t0] = w_;                \
        }                                                                        \
        float s_m1 = 0.f, s_0 = 0.f;                                             \
        _Pragma("unroll")                                                        \
        for (int e = 0; e < 4; e++) {                                            \
            float x_m2 = pm2[e], x_m1 = pm1[e];                                  \
            float x0 = ((float*)&Ax)[e], x1 = ((float*)&Ay)[e];                  \
            float m_a = fmaf(cw0[e], x_m2, fmaf(cw1[e], x_m1, fmaf(cw2[e], x0, cb4[e]))); \
            float v_a = m_a + x_m1; v_a = v_a > 0.f ? v_a : 0.f;                 \
            s_m1 = fmaf(v_a, lw4[e], s_m1);                                      \
            float m_b = fmaf(cw0[e], x_m1, fmaf(cw1[e], x0, fmaf(cw2[e], x1, cb4[e]))); \
            float v_b = m_b + x0; v_b = v_b > 0.f ? v_b : 0.f;                   \
            s_0 = fmaf(v_b, lw4[e], s_0);                                        \
        }                                                                        \
        _Pragma("unroll")                                                        \
        for (int off = 1; off <= 4; off <<= 1) {                                 \
            s_m1 += __shfl_xor(s_m1, off, 64);                                   \
            s_0  += __shfl_xor(s_0, off, 64);                                    \
        }                                                                        \
        if (dl == 0) {                                                           \
            if (t0 > 0) al_s[t0 - 1] = s_m1;                                     \
            al_s[t0] = s_0;                                                      \
        }                                                                        \
        Lp0 = Ax; Lp1 = Ay; }

    PROC(0, xa0, xa1) LOADP(xa0, xa1, 3)
    PROC(1, xb0, xb1) LOADP(xb0, xb1, 4)
    PROC(2, xc0, xc1) LOADP(xc0, xc1, 5)
    PROC(3, xa0, xa1) LOADP(xa0, xa1, 6)
    PROC(4, xb0, xb1) LOADP(xb0, xb1, 7)
    PROC(5, xc0, xc1)
    PROC(6, xa0, xa1)
    PROC(7, xb0, xb1)
    #undef PROC
    #undef LOADP

    // final t = 2047 (conv window h[2046], h[2047], 0-pad); Lp holds pass-7 pair
    if (wave == 15 && q == 7) {
        float sacc = 0.f;
        #pragma unroll
        for (int e = 0; e < 4; e++) {
            float xm1 = ((float*)&Lp0)[e];   // h[2046]
            float x0  = ((float*)&Lp1)[e];   // h[2047]
            float m = fmaf(cw0[e], xm1, fmaf(cw1[e], x0, cb4[e]));
            float v = m + x0; v = v > 0.f ? v : 0.f;
            sacc = fmaf(v, lw4[e], sacc);
        }
        #pragma unroll
        for (int off = 1; off <= 4; off <<= 1) sacc += __shfl_xor(sacc, off, 64);
        if (dl == 0) al_s[kT - 1] = sacc;
    }
    __syncthreads();                              // al_s scratch complete

    // coalesced hardware-fp atomic burst: 2048 contiguous 4-B RMWs per block
    {
        float2 pv = ((const float2*)al_s)[tid];
        unsafeAtomicAdd(pacc + 2 * tid, pv.x);
        unsafeAtomicAdd(pacc + 2 * tid + 1, pv.y);
    }

    // ---- grid barrier (256 blocks, all resident; bounded spin) ----
    // __syncthreads drains vmcnt(0) => this block's atomics performed at IF.
    __syncthreads();
    if (tid == 0) {
        __hip_atomic_fetch_add(counter, 1u, __ATOMIC_RELEASE, __HIP_MEMORY_SCOPE_AGENT);
        long long guard = 0;
        while (__hip_atomic_load(counter, __ATOMIC_RELAXED, __HIP_MEMORY_SCOPE_AGENT) < (unsigned)kNB) {
            __builtin_amdgcn_s_sleep(2);
            if (++guard > (3LL << 20)) break;   // safety valve
        }
    }
    __syncthreads();

    // ---- Phase B: load summed logits -> sigmoid -> scan -> al_s -> banded MFMA ----
    const int lm = lane & 15, quad = lane >> 4;
    const float sig = sigma[h];
    const float sigL = sig * 1.2011224f;          // sig * sqrt(log2 e)
    const float lb = lin_b[0];

    union { unsigned long long u; float2 f; } cv;
    cv.u = __hip_atomic_load((const unsigned long long*)(pacc + 2 * tid),
                             __ATOMIC_RELAXED, __HIP_MEMORY_SCOPE_AGENT);
    float2 mv = ((const float2*)(mask + (size_t)b * kT))[tid];
    float aw0 = (1.f / (1.f + expf(-(cv.f.x + lb)))) * mv.x;  // relu(sigmoid*1-0)==sigmoid
    float aw1 = (1.f / (1.f + expf(-(cv.f.y + lb)))) * mv.y;

    const float p0 = aw0, p1v = aw0 + aw1;
    float sc = p1v;
    #pragma unroll
    for (int off = 1; off <= 32; off <<= 1) {
        float v = __shfl_up(sc, off, 64);
        sc = (lane >= off) ? sc + v : sc;
    }
    if (lane == 63) woff[wave] = sc;
    __syncthreads();
    if (tid == 0) {
        float run = 0.f;
        #pragma unroll
        for (int w = 0; w < 16; w++) { float x = woff[w]; woff[w] = run; run += x; }
        s_tot = run;
    }
    __syncthreads();
    const float tot = s_tot;
    const float scale = (tot != 0.f) ? ((float)target[b] / tot) : 0.f;
    const float basev = woff[wave] + (sc - p1v);
    {
        float c0 = (basev + p0) * scale;
        float c1 = (basev + p1v) * scale;
        float2 alv;
        alv.x = (mv.x > 0.f) ? c0 : 1.0e30f;
        alv.y = (mv.y > 0.f) ? c1 : 1.0e30f;
        ((float2*)al_s)[tid] = alv;
    }
    if (ds == 0 && h == 0) {
        if (tid == 0) out_tok[b] = tot;
        float2 oa; oa.x = aw0 * scale; oa.y = aw1 * scale;
        ((float2*)(out_alpha + (size_t)b * kT))[tid] = oa;
    }
    __syncthreads();

    // per-lane u: exact softmax max via binary search (al_s monotone)
    const int u_base = wave * 16;
    const float du = (float)(u_base + lm) + 0.5f;
    const float duL = du * sigL;
    int pos = 0;
    #pragma unroll
    for (int stp = 1024; stp >= 1; stp >>= 1) {
        int np = pos + stp;
        pos = (al_s[np - 1] < du) ? np : pos;
    }
    float d1 = (pos < kT) ? al_s[pos] - du : 3.0e30f;
    float d0 = (pos > 0) ? du - al_s[pos - 1] : 3.0e30f;
    float dmin = fminf(d0, d1);
    float ms = fminf(dmin, 1.0e4f) * sigL;
    const float mu_pos = ms * ms;                    // = -max_score in log2 units

    // wave band: |du - al| <= sqrt(dmax^2 + 21/sig^2)   (natural-log e-folds)
    float dmax_l = fminf(dmin, 1.0e4f);
    #pragma unroll
    for (int off = 8; off >= 1; off >>= 1) dmax_l = fmaxf(dmax_l, __shfl_xor(dmax_l, off, 64));
    const float c21 = (sig > 1e-3f) ? 21.0f / (sig * sig) : 9.0e60f;
    const float bound = sqrtf(fmaf(dmax_l, dmax_l, c21));
    const float lo_b = (float)u_base + 0.5f - bound;
    const float hi_b = (float)u_base + 15.5f + bound;
    int p_lo = 0, p_hi = 0;
    #pragma unroll
    for (int stp = 1024; stp >= 1; stp >>= 1) {
        int n1 = p_lo + stp; p_lo = (al_s[n1 - 1] < lo_b) ? n1 : p_lo;
        int n2 = p_hi + stp; p_hi = (al_s[n2 - 1] < hi_b) ? n2 : p_hi;
    }
    const int ks_lo = p_lo >> 5;
    const int ks_end = (p_hi + 31) >> 5;

    float4v acc0 = (float4v)(0.f), acc1 = (float4v)(0.f);
    float lsum = 0.f;

    for (int kg = ks_lo; kg < ks_end; kg++) {
        const int kb = kg * 32;
        float alv[8];
        *(float4*)&alv[0] = *(const float4*)&al_s[kb + quad * 8];
        *(float4*)&alv[4] = *(const float4*)&al_s[kb + quad * 8 + 4];

        float ev[8];
        #pragma unroll
        for (int j = 0; j < 8; j++) {
            float d = fmaf(-alv[j], sigL, duL);       // (du - al) * sigL
            float e = exp2_fast(fmaf(-d, d, mu_pos)); // 2^(mu' - d'^2) <= 1
            lsum += e;
            ev[j] = e;
        }
        union { short8 s; unsigned int w[4]; } af;
        af.w[0] = pk_bf16(ev[0], ev[1]);
        af.w[1] = pk_bf16(ev[2], ev[3]);
        af.w[2] = pk_bf16(ev[4], ev[5]);
        af.w[3] = pk_bf16(ev[6], ev[7]);
        short8 bf0 = *(const short8*)&bV[lm * kPitch + kb + quad * 8];
        short8 bf1 = *(const short8*)&bV[(16 + lm) * kPitch + kb + quad * 8];
        acc0 = __builtin_amdgcn_mfma_f32_16x16x32_bf16(af.s, bf0, acc0, 0, 0, 0);
        acc1 = __builtin_amdgcn_mfma_f32_16x16x32_bf16(af.s, bf1, acc1, 0, 0, 0);
    }

    // epilogue: reduce l across quads, normalize, direct store (disjoint)
    float lv = lsum;
    lv += __shfl_xor(lv, 16, 64);
    lv += __shfl_xor(lv, 32, 64);
    #pragma unroll
    for (int r = 0; r < 4; r++) {
        const int ur = quad * 4 + r;
        float rl = __shfl(lv, ur, 64);
        float linv = (rl > 1e-30f) ? 1.f / rl : 0.f;
        const int u = u_base + ur;
        if (u < kU) {
            float* dst = out_ac + ((size_t)(b * kU + u)) * kC + h * kDH + ds * kDW + lm;
            dst[0]  = acc0[r] * linv;
            dst[16] = acc1[r] * linv;
        }
    }
}

extern "C" void kernel_launch(void* const* d_in, const int* in_sizes, int n_in,
                              void* d_out, int out_size, void* d_ws, size_t ws_size,
                              hipStream_t stream) {
    const float* hid    = (const float*)d_in[0];
    const float* mask   = (const float*)d_in[1];
    const int*   tgt    = (const int*)d_in[2];
    // d_in[3] = max_token scalar (compile-time kU=250)
    const float* conv_w = (const float*)d_in[4];
    const float* conv_b = (const float*)d_in[5];
    const float* lin_w  = (const float*)d_in[6];
    const float* lin_b  = (const float*)d_in[7];
    const float* sigma  = (const float*)d_in[8];
    // d_in[9] = sigma_bias: constant over t -> cancels in softmax; unused.

    unsigned int* counter = (unsigned int*)d_ws;               // 256 B (zeroed)
    float* part = (float*)((char*)d_ws + 256);                 // [B][T] summed logits (zeroed)

    float* out_ac    = (float*)d_out;                          // [B, U, C]
    float* out_tok   = out_ac + (size_t)kB * kU * kC;          // [B]
    float* out_alpha = out_tok + kB;                           // [B, T]

    // zero grid-barrier counter + atomic accumulator (graph-capturable node)
    hipMemsetAsync(d_ws, 0, 256 + (size_t)kB * kT * 4, stream);
    fused_pif<<<dim3(kDS, kH, kB), 1024, 0, stream>>>(
        hid, mask, tgt, sigma, conv_w, conv_b, lin_w, lin_b,
        part, counter, out_ac, out_tok, out_alpha);
}